// Round 6
// baseline (678.482 us; speedup 1.0000x reference)
//
#include <hip/hip_runtime.h>
#include <hip/hip_cooperative_groups.h>
#include <math.h>

namespace cg = cooperative_groups;

// Dims (CLEVR-scale, fixed)
#define BB 128
#define NN 36
#define DF 512
#define DE 256
#define DV 512
#define HH 256
#define NCC 28
#define LQ 5
#define NE 1296           // N*N edges per batch
#define SCALE 0.04419417382415922f   // 1/sqrt(512)

#define ETILES 10368      // 128 batches * 81 tiles of 16 edges
#define GRID 256          // 1 block/CU (128 KiB LDS), cooperative
#define NODE_PAIRS 144    // 288 node tiles, 2 per 512-thr block

typedef __bf16 bf16_8 __attribute__((ext_vector_type(8)));
typedef float  f32_4  __attribute__((ext_vector_type(4)));

__device__ __forceinline__ float sigmoidf_(float x){ return 1.0f/(1.0f + expf(-x)); }
__device__ __forceinline__ float reluf_(float x){ return x > 0.f ? x : 0.f; }

__device__ __forceinline__ bf16_8 cvt8(f32_4 f0, f32_4 f1){
    bf16_8 v;
    #pragma unroll
    for (int i=0;i<4;i++){ v[i] = (__bf16)f0[i]; v[i+4] = (__bf16)f1[i]; }
    return v;
}
// hi/lo split of 8 fp32 into two bf16_8 (3-term split-bf16 emulation, ~2^-18 rel err)
__device__ __forceinline__ void split8(f32_4 f0, f32_4 f1, bf16_8& h, bf16_8& l){
    #pragma unroll
    for (int i=0;i<4;i++){
        __bf16 hi = (__bf16)f0[i];
        h[i] = hi; l[i] = (__bf16)(f0[i] - (float)hi);
        __bf16 hi2 = (__bf16)f1[i];
        h[i+4] = hi2; l[i+4] = (__bf16)(f1[i] - (float)hi2);
    }
}

// async global->LDS DMA, 16B/lane. LDS dest = lds_base + lane*16 (wave-uniform base).
__device__ __forceinline__ void async_copy16(const float* g, float* lds_base){
    __builtin_amdgcn_global_load_lds(
        (const __attribute__((address_space(1))) void*)g,
        (__attribute__((address_space(3))) void*)lds_base, 16, 0, 0);
}

#define XROW 516   // 512 + 4 dwords pad (516 mod 32 == 4 -> uniform banks on frag reads)

// ---------------------------------------------------------------------------
// node MLP body on a 256-thread slice (t in 0..255), proven in rounds 0/5
// ---------------------------------------------------------------------------
__device__ __forceinline__ void node_body(
    int nb, char* smem, int t,
    const float* __restrict__ X,
    const __bf16* __restrict__ W1h, const __bf16* __restrict__ W1l,
    const float* __restrict__ b1,
    const __bf16* __restrict__ W2h, const __bf16* __restrict__ W2l,
    const float* __restrict__ b2,
    float* __restrict__ nf)
{
    float* xs  = (float*)smem;                    // 16 x XROW fp32 (33024 B)
    __bf16* hh = (__bf16*)(smem + 33024);         // 8 KB
    __bf16* hl = (__bf16*)(smem + 41216);         // 8 KB
    int r0 = nb*16, wv = t>>6, lane = t&63;
    int m = lane&15, kc = lane>>4;
    int q = lane>>4, c = lane&15;

    #pragma unroll
    for (int r=0;r<4;r++){
        int row = wv*4 + r;
        const float* src = X + (size_t)(r0+row)*DF + lane*4;
        async_copy16(src,       &xs[row*XROW]);
        async_copy16(src + 256, &xs[row*XROW + 256]);
    }
    __syncthreads();

    f32_4 zero = {0.f,0.f,0.f,0.f};
    f32_4 acc1[4];
    #pragma unroll
    for (int nt=0;nt<4;nt++) acc1[nt] = zero;
    for (int kt=0; kt<16; kt++){
        const float* ap = &xs[m*XROW + kt*32 + kc*8];
        f32_4 f0 = *(const f32_4*)ap;
        f32_4 f1 = *(const f32_4*)(ap+4);
        bf16_8 ah, al;
        split8(f0, f1, ah, al);
        #pragma unroll
        for (int nt=0;nt<4;nt++){
            size_t bo = ((size_t)(kt*16 + wv*4+nt)*64 + lane)*8;
            bf16_8 bh = *(const bf16_8*)(W1h + bo);
            bf16_8 bl = *(const bf16_8*)(W1l + bo);
            acc1[nt] = __builtin_amdgcn_mfma_f32_16x16x32_bf16(ah, bh, acc1[nt], 0,0,0);
            acc1[nt] = __builtin_amdgcn_mfma_f32_16x16x32_bf16(al, bh, acc1[nt], 0,0,0);
            acc1[nt] = __builtin_amdgcn_mfma_f32_16x16x32_bf16(ah, bl, acc1[nt], 0,0,0);
        }
    }
    #pragma unroll
    for (int nt=0;nt<4;nt++){
        int col = wv*64 + nt*16 + c;
        float bias = b1[col];
        int kt2 = col>>5, j2 = col&7;
        int lbase = ((col&31)>>3)*16;
        #pragma unroll
        for (int r=0;r<4;r++){
            int row = q*4 + r;
            float v = reluf_(acc1[nt][r] + bias);
            __bf16 hi = (__bf16)v;
            int off = (kt2*64 + lbase + row)*8 + j2;
            hh[off] = hi;
            hl[off] = (__bf16)(v - (float)hi);
        }
    }
    __syncthreads();

    f32_4 acc2[8];
    #pragma unroll
    for (int nt=0;nt<8;nt++) acc2[nt] = zero;
    for (int kt=0; kt<8; kt++){
        bf16_8 ah = *(const bf16_8*)&hh[(kt*64+lane)*8];
        bf16_8 al = *(const bf16_8*)&hl[(kt*64+lane)*8];
        #pragma unroll
        for (int nt=0;nt<8;nt++){
            size_t bo = ((size_t)(kt*32 + wv*8+nt)*64 + lane)*8;
            bf16_8 bh = *(const bf16_8*)(W2h + bo);
            bf16_8 bl = *(const bf16_8*)(W2l + bo);
            acc2[nt] = __builtin_amdgcn_mfma_f32_16x16x32_bf16(ah, bh, acc2[nt], 0,0,0);
            acc2[nt] = __builtin_amdgcn_mfma_f32_16x16x32_bf16(al, bh, acc2[nt], 0,0,0);
            acc2[nt] = __builtin_amdgcn_mfma_f32_16x16x32_bf16(ah, bl, acc2[nt], 0,0,0);
        }
    }
    #pragma unroll
    for (int nt=0;nt<8;nt++){
        int col = wv*128 + nt*16 + c;
        float bias = b2[col];
        #pragma unroll
        for (int r=0;r<4;r++){
            int row = q*4 + r;
            nf[(size_t)(r0+row)*DV + col] = acc2[nt][r] + bias;
        }
    }
}

// ---------------------------------------------------------------------------
// edge body: persistent streaming, single-pass acc[16], atomic work queue.
// Spill hygiene (rounds 2-5 lesson): #pragma unroll 1 on kt loop so the
// scheduler cannot hoist more than one iteration's ds_reads/loads.
// Peak live ~ acc 64 + pipeline 16 + B transients + addr ~ 110 < 128.
// E read once per tile; one vmcnt convoy point per kt iter, covered by
// 16 MFMAs + 16 ds_reads.
// ---------------------------------------------------------------------------
__device__ __forceinline__ void edge_body(
    char* smem,
    const float* __restrict__ E, const __bf16* __restrict__ Wp,
    const float* __restrict__ b_e1, const float* __restrict__ ve,
    const float* __restrict__ se, float* __restrict__ weit,
    int* __restrict__ ctr)
{
    __bf16* wlds = (__bf16*)smem;   // 131072 B packed W_e1
    int t = threadIdx.x, wv = t>>6, lane = t&63;
    int m = lane&15, kc = lane>>4;

    // stage full packed W_e1: 128 chunks of 1KB; wave wv does chunks wv*16..+16
    #pragma unroll
    for (int i=0;i<16;i++){
        int off = (wv*16 + i) << 10;   // byte offset
        async_copy16((const float*)((const char*)Wp + off) + lane*4,
                     (float*)((char*)wlds + off));
    }
    __syncthreads();

    for(;;){
        int tile;
        if (lane == 0) tile = atomicAdd(ctr, 1);
        tile = __shfl(tile, 0, 64);
        if (tile >= ETILES) break;

        int b = tile/81, tt = tile - b*81;
        int e0 = tt*16;
        // A-frag base: row (edge) = lane&15, k-offset = (lane>>4)*8, per kt +32 floats
        const float* Ea = E + ((size_t)b*NE + e0 + m)*DE + kc*8;
        float seb = se[b];

        f32_4 zero = {0.f,0.f,0.f,0.f};
        f32_4 acc[16];
        #pragma unroll
        for (int nt=0;nt<16;nt++) acc[nt] = zero;

        f32_4 c0 = *(const f32_4*)Ea;
        f32_4 c1 = *(const f32_4*)(Ea + 4);
        #pragma unroll 1
        for (int kt=0;kt<8;kt++){
            int kn = (kt+1)&7;   // branchless prefetch (kt=7 reads kt=0, discarded)
            f32_4 n0 = *(const f32_4*)(Ea + kn*32);
            f32_4 n1 = *(const f32_4*)(Ea + kn*32 + 4);
            bf16_8 af = cvt8(c0, c1);
            const __bf16* wb = wlds + ((size_t)(kt*16)*64 + lane)*8;
            #pragma unroll
            for (int nt=0;nt<16;nt++){
                bf16_8 bfrag = *(const bf16_8*)(wb + (size_t)nt*512);
                acc[nt] = __builtin_amdgcn_mfma_f32_16x16x32_bf16(af, bfrag, acc[nt], 0,0,0);
            }
            c0 = n0; c1 = n1;
        }

        float s0=0.f, s1=0.f, s2=0.f, s3=0.f;
        #pragma unroll
        for (int nt=0;nt<16;nt++){
            int h = nt*16 + m;
            float bev = b_e1[h];
            float vev = ve[b*HH + h];
            s0 = fmaf(reluf_(acc[nt][0] + bev), vev, s0);
            s1 = fmaf(reluf_(acc[nt][1] + bev), vev, s1);
            s2 = fmaf(reluf_(acc[nt][2] + bev), vev, s2);
            s3 = fmaf(reluf_(acc[nt][3] + bev), vev, s3);
        }
        #pragma unroll
        for (int off=1; off<16; off<<=1){
            s0 += __shfl_xor(s0, off, 64);
            s1 += __shfl_xor(s1, off, 64);
            s2 += __shfl_xor(s2, off, 64);
            s3 += __shfl_xor(s3, off, 64);
        }
        if (m == 0){
            f32_4 o;
            o[0] = sigmoidf_((s0 + seb)*SCALE);
            o[1] = sigmoidf_((s1 + seb)*SCALE);
            o[2] = sigmoidf_((s2 + seb)*SCALE);
            o[3] = sigmoidf_((s3 + seb)*SCALE);
            *(f32_4*)&weit[(size_t)b*NE + e0 + kc*4] = o;
        }
    }
}

// ---------------------------------------------------------------------------
// attention chain + head per batch (512 thr), shared arrays carved from smem
// ---------------------------------------------------------------------------
__device__ __forceinline__ void attnhead_body(
    char* smem, int b,
    const float* __restrict__ nf, const float* __restrict__ qws,
    const float* __restrict__ weit,
    const float* __restrict__ Wq,  const float* __restrict__ bq,
    const float* __restrict__ Wc1, const float* __restrict__ bc1,
    const float* __restrict__ Wc2, const float* __restrict__ bc2,
    float* __restrict__ out)
{
    float* a1  = (float*)smem;         // 64 (36 used)
    float* a2  = a1 + 64;
    float* a3  = a2 + 64;
    float* xsh = a3 + 64;              // 512
    float* osh = xsh + 512;            // 512
    float* hsh = osh + 512;            // 256
    float* dn  = hsh + 256;            // 1
    int t = threadIdx.x;
    int wv = t>>6, lane = t&63;
    const float* nfb = nf + (size_t)b*NN*DV;
    const float* q0 = qws + ((size_t)(b*4+0))*DV;
    const float* q1 = qws + ((size_t)(b*4+1))*DV;
    const float* q3 = qws + ((size_t)(b*4+3))*DV;

    for (int i=wv; i<NN; i+=8){
        const float* row = nfb + (size_t)i*DV + lane*8;
        const float* qq  = q3 + lane*8;
        f32_4 x0 = *(const f32_4*)row, x1 = *(const f32_4*)(row+4);
        f32_4 y0 = *(const f32_4*)qq,  y1 = *(const f32_4*)(qq+4);
        float p = x0[0]*y0[0] + x0[1]*y0[1] + x0[2]*y0[2] + x0[3]*y0[3]
                + x1[0]*y1[0] + x1[1]*y1[1] + x1[2]*y1[2] + x1[3]*y1[3];
        #pragma unroll
        for (int off=32; off; off>>=1) p += __shfl_xor(p, off, 64);
        if (lane==0) a1[i] = sigmoidf_(p*SCALE);
    }
    __syncthreads();
    if (t < NN){
        const float* wrow = weit + (size_t)b*NE;
        float s = 0.f;
        #pragma unroll
        for (int i=0;i<NN;i++) s = fmaf(a1[i], wrow[i*NN + t], s);
        a2[t] = fminf(fmaxf(s, 0.f), 1.f);
    }
    __syncthreads();
    for (int i=wv; i<NN; i+=8){
        const float* row = nfb + (size_t)i*DV + lane*8;
        const float* qq  = q1 + lane*8;
        f32_4 x0 = *(const f32_4*)row, x1 = *(const f32_4*)(row+4);
        f32_4 y0 = *(const f32_4*)qq,  y1 = *(const f32_4*)(qq+4);
        float p = x0[0]*y0[0] + x0[1]*y0[1] + x0[2]*y0[2] + x0[3]*y0[3]
                + x1[0]*y1[0] + x1[1]*y1[1] + x1[2]*y1[2] + x1[3]*y1[3];
        #pragma unroll
        for (int off=32; off; off>>=1) p += __shfl_xor(p, off, 64);
        if (lane==0) a3[i] = a2[i]*sigmoidf_(p*SCALE);
    }
    __syncthreads();
    if (t==0){
        float s = 0.f;
        for (int i=0;i<NN;i++) s += a3[i];
        dn[0] = 1.f/(s + 1e-8f);
    }
    __syncthreads();
    if (t < NN) a3[t] *= dn[0];
    __syncthreads();

    // pooled + gate by q0: thread t owns dim t (512 dims)
    {
        float p = 0.f;
        #pragma unroll 4
        for (int i=0;i<NN;i++) p = fmaf(a3[i], nfb[(size_t)i*DV + t], p);
        xsh[t] = p * q0[t];
    }
    __syncthreads();

    // GEMV1: o = relu(x @ Wq + bq), col t
    {
        float acc = bq[t];
        #pragma unroll 8
        for (int k=0;k<DV;k++) acc = fmaf(xsh[k], Wq[(size_t)k*DV + t], acc);
        osh[t] = reluf_(acc);
    }
    __syncthreads();

    // GEMV2: h = relu(o @ Wc1 + bc1), cols 0..255
    if (t < HH){
        float acc = bc1[t];
        #pragma unroll 8
        for (int k=0;k<DV;k++) acc = fmaf(osh[k], Wc1[(size_t)k*HH + t], acc);
        hsh[t] = reluf_(acc);
    }
    __syncthreads();

    // GEMV3: out = h @ Wc2 + bc2, cols 0..27
    if (t < NCC){
        float acc = bc2[t];
        #pragma unroll 8
        for (int k=0;k<HH;k++) acc = fmaf(hsh[k], Wc2[(size_t)k*NCC + t], acc);
        out[(size_t)b*NCC + t] = acc;
    }
}

// ---------------------------------------------------------------------------
// ONE cooperative kernel: phase0 setup -> grid.sync -> phase1 node+edge
// (atomic work queue) -> grid.sync -> phase2 attn+head.
// 256 blocks x 512 thr, 1 block/CU (131 KiB LDS) -> cooperative-legal.
// ---------------------------------------------------------------------------
__global__ __launch_bounds__(512, 1) void k_all(
    const float* __restrict__ E, const float* __restrict__ X,
    const float* __restrict__ W_n1, const float* __restrict__ b_n1,
    const float* __restrict__ W_n2, const float* __restrict__ b_n2,
    const float* __restrict__ W_e1, const float* __restrict__ b_e1,
    const float* __restrict__ W_e2, const float* __restrict__ b_e2,
    const float* __restrict__ W_q,  const float* __restrict__ b_q,
    const float* __restrict__ W_c1, const float* __restrict__ b_c1,
    const float* __restrict__ W_c2, const float* __restrict__ b_c2,
    const float* __restrict__ word_emb, const int* __restrict__ program_inputs,
    __bf16* __restrict__ Pn1h, __bf16* __restrict__ Pn1l,
    __bf16* __restrict__ Pn2h, __bf16* __restrict__ Pn2l,
    __bf16* __restrict__ Peh,
    float* __restrict__ qws, float* __restrict__ ve, float* __restrict__ se,
    float* __restrict__ nf, float* __restrict__ weit,
    int* __restrict__ ctr, float* __restrict__ out)
{
    cg::grid_group grid = cg::this_grid();
    __shared__ __align__(16) char smem[131072];
    int bx = blockIdx.x;

    // ---------------- phase 0: setup (vbid = bx*2 + slice, 0..511) ----------
    {
        int sub = threadIdx.x >> 8, t = threadIdx.x & 255;
        int vbid = bx*2 + sub;
        if (vbid < 160){
            // pack W_n1 / W_n2 / W_e1 into MFMA fragment order (bf16 h/l)
            const float* W; __bf16 *Ph, *Pl; int N, base, realN;
            if (vbid < 64)       { W=W_n1; Ph=Pn1h; Pl=Pn1l; N=256; base=0;   realN=256; }
            else if (vbid < 128) { W=W_n2; Ph=Pn2h; Pl=Pn2l; N=512; base=64;  realN=512; }
            else                 { W=W_e1; Ph=Peh;  Pl=nullptr; N=256; base=128; realN=256; }
            int g = (vbid-base)*256 + t;
            int lane = g & 63, slot = g >> 6;
            int NT = N >> 4;
            int nt = slot % NT, kt = slot / NT;
            int krow = kt*32 + (lane>>4)*8, ncol = nt*16 + (lane&15);
            #pragma unroll
            for (int j=0;j<8;j++){
                float w = (ncol < realN) ? W[(size_t)(krow+j)*realN + ncol] : 0.f;
                __bf16 hi = (__bf16)w;
                Ph[(size_t)g*8+j] = hi;
                if (Pl) Pl[(size_t)g*8+j] = (__bf16)(w - (float)hi);
            }
        } else if (vbid < 288){
            // prep: qws / ve / se per batch (slice-local reduction buffer)
            __shared__ float red[2][4];
            int b = vbid - 160, wv = t>>6, lane = t&63;
            int idx[4];
            #pragma unroll
            for (int k=0;k<4;k++) idx[k] = program_inputs[b*LQ + k];
            #pragma unroll
            for (int k=0;k<4;k++){
                qws[((size_t)(b*4+k))*DV + t]       = word_emb[(size_t)idx[k]*DV + t];
                qws[((size_t)(b*4+k))*DV + t + 256] = word_emb[(size_t)idx[k]*DV + t + 256];
            }
            const float* q2p = word_emb + (size_t)idx[2]*DV + lane*8;
            f32_4 qa = *(const f32_4*)q2p, qb = *(const f32_4*)(q2p+4);
            for (int i=0;i<64;i++){
                int h = wv*64 + i;
                const float* wr = W_e2 + (size_t)h*DV + lane*8;
                f32_4 a = *(const f32_4*)wr, c = *(const f32_4*)(wr+4);
                float p = a[0]*qa[0] + a[1]*qa[1] + a[2]*qa[2] + a[3]*qa[3]
                        + c[0]*qb[0] + c[1]*qb[1] + c[2]*qb[2] + c[3]*qb[3];
                #pragma unroll
                for (int off=32; off; off>>=1) p += __shfl_xor(p, off, 64);
                if (lane==0) ve[b*HH + h] = p;
            }
            float pp = b_e2[t]*word_emb[(size_t)idx[2]*DV + t]
                     + b_e2[t+256]*word_emb[(size_t)idx[2]*DV + t + 256];
            #pragma unroll
            for (int off=32; off; off>>=1) pp += __shfl_down(pp, off, 64);
            if ((t&63)==0) red[sub][t>>6] = pp;
            __syncthreads();
            if (t==0) se[b] = red[sub][0]+red[sub][1]+red[sub][2]+red[sub][3];
        }
        if (bx == GRID-1 && threadIdx.x == 0) *ctr = 0;
    }
    __threadfence();
    grid.sync();

    // ---------------- phase 1: node (blocks 0..143) + edge (all, queued) ----
    {
        if (bx < NODE_PAIRS){
            int sub = threadIdx.x >> 8;
            int nb = bx*2 + sub;     // node tile 0..287
            node_body(nb, smem + sub*49408, threadIdx.x & 255,
                      X, Pn1h, Pn1l, b_n1, Pn2h, Pn2l, b_n2, nf);
            __syncthreads();
        }
        edge_body(smem, E, Peh, b_e1, ve, se, weit, ctr);
    }
    __threadfence();
    grid.sync();

    // ---------------- phase 2: attention + head (blocks 0..127) -------------
    if (bx < BB){
        attnhead_body(smem, bx, nf, qws, weit,
                      W_q, b_q, W_c1, b_c1, W_c2, b_c2, out);
    }
}

// ---------------------------------------------------------------------------
extern "C" void kernel_launch(void* const* d_in, const int* in_sizes, int n_in,
                              void* d_out, int out_size, void* d_ws, size_t ws_size,
                              hipStream_t stream)
{
    const float* node_feats = (const float*)d_in[0];
    const float* edge_feats = (const float*)d_in[1];
    const float* W_n1 = (const float*)d_in[2];
    const float* b_n1 = (const float*)d_in[3];
    const float* W_n2 = (const float*)d_in[4];
    const float* b_n2 = (const float*)d_in[5];
    const float* W_e1 = (const float*)d_in[6];
    const float* b_e1 = (const float*)d_in[7];
    const float* W_e2 = (const float*)d_in[8];
    const float* b_e2 = (const float*)d_in[9];
    const float* W_q  = (const float*)d_in[10];
    const float* b_q  = (const float*)d_in[11];
    const float* W_c1 = (const float*)d_in[12];
    const float* b_c1 = (const float*)d_in[13];
    const float* W_c2 = (const float*)d_in[14];
    const float* b_c2 = (const float*)d_in[15];
    const float* word_emb = (const float*)d_in[16];
    const int* program_inputs = (const int*)d_in[18];

    // workspace layout (all chunks 256B-aligned)
    char* ws = (char*)d_ws;
    float* qws  = (float*)ws; ws += (size_t)BB*4*DV*4;        // 1 MB
    float* ve   = (float*)ws; ws += (size_t)BB*HH*4;          // 128 KB
    float* se   = (float*)ws; ws += 512;
    __bf16* Pn1h = (__bf16*)ws; ws += (size_t)DF*HH*2;        // 256 KB
    __bf16* Pn1l = (__bf16*)ws; ws += (size_t)DF*HH*2;
    __bf16* Pn2h = (__bf16*)ws; ws += (size_t)HH*DV*2;
    __bf16* Pn2l = (__bf16*)ws; ws += (size_t)HH*DV*2;
    __bf16* Peh  = (__bf16*)ws; ws += (size_t)DE*HH*2;        // 128 KB
    float* nf   = (float*)ws; ws += (size_t)BB*NN*DV*4;       // 9 MB
    float* weit = (float*)ws; ws += (size_t)BB*NE*4;          // 648 KB
    int*   ctr  = (int*)ws;   ws += 256;
    float* out_f = (float*)d_out;

    void* args[] = {
        (void*)&edge_feats, (void*)&node_feats,
        (void*)&W_n1, (void*)&b_n1, (void*)&W_n2, (void*)&b_n2,
        (void*)&W_e1, (void*)&b_e1, (void*)&W_e2, (void*)&b_e2,
        (void*)&W_q,  (void*)&b_q,  (void*)&W_c1, (void*)&b_c1,
        (void*)&W_c2, (void*)&b_c2, (void*)&word_emb, (void*)&program_inputs,
        (void*)&Pn1h, (void*)&Pn1l, (void*)&Pn2h, (void*)&Pn2l, (void*)&Peh,
        (void*)&qws, (void*)&ve, (void*)&se, (void*)&nf, (void*)&weit,
        (void*)&ctr, (void*)&out_f
    };
    hipLaunchCooperativeKernel((const void*)k_all, dim3(GRID), dim3(512),
                               args, 0, stream);
}